// Round 16
// baseline (478.172 us; speedup 1.0000x reference)
//
#include <hip/hip_runtime.h>
#include <hip/hip_bf16.h>

typedef unsigned short u16;
typedef unsigned int u32;
typedef u16 u16x8 __attribute__((ext_vector_type(8)));
typedef float f32x4 __attribute__((ext_vector_type(4)));

__device__ __forceinline__ u16 f2bf(float f) {
  union { float f; u32 u; } v; v.f = f;
  u32 r = v.u + 0x7FFFu + ((v.u >> 16) & 1u);
  return (u16)(r >> 16);
}
__device__ __forceinline__ float bf2f(u16 h) {
  union { u32 u; float f; } v; v.u = ((u32)h) << 16;
  return v.f;
}
__device__ __forceinline__ void mfma_bf16_16x16x32(f32x4& acc, const f32x4& a, const f32x4& b) {
  asm("v_mfma_f32_16x16x32_bf16 %0, %1, %2, %0" : "+v"(acc) : "v"(a), "v"(b));
}
__device__ __forceinline__ void gload_lds16(const void* g, void* l) {
  __builtin_amdgcn_global_load_lds(
      (const __attribute__((address_space(1))) unsigned int*)g,
      (__attribute__((address_space(3))) unsigned int*)l, 16, 0, 0);
}

// ---------------- fp32 -> bf16 weight converts (ONE dispatch) -------------
__device__ __forceinline__ u16x8 cvt_row8(const float* p) {
  float4 f0 = *(const float4*)p;
  float4 f1 = *(const float4*)(p + 4);
  u16x8 o;
  o[0] = f2bf(f0.x); o[1] = f2bf(f0.y); o[2] = f2bf(f0.z); o[3] = f2bf(f0.w);
  o[4] = f2bf(f1.x); o[5] = f2bf(f1.y); o[6] = f2bf(f1.z); o[7] = f2bf(f1.w);
  return o;
}

// bid<8192: wq|wk|wv|wo rows -> WQKVb; <24576: w1/w3 interleave -> W13b;
// else: w2 flat -> W2b.  Per-block-uniform branch (no divergence).
__global__ __launch_bounds__(256) void cvt_all(
    const float* __restrict__ wq, const float* __restrict__ wk,
    const float* __restrict__ wv, const float* __restrict__ wo,
    const float* __restrict__ w1, const float* __restrict__ w3,
    const float* __restrict__ w2, u16* __restrict__ WQKVb,
    u16* __restrict__ W13b, u16* __restrict__ W2b) {
  int bid = blockIdx.x;
  int t = threadIdx.x;
  if (bid < 8192) {
    const float* s = (bid < 2048) ? wq : (bid < 4096) ? wk : (bid < 6144) ? wv : wo;
    int r = bid & 2047;
    *(u16x8*)&WQKVb[(size_t)bid * 2048 + t * 8] =
        cvt_row8(s + (size_t)r * 2048 + t * 8);
  } else if (bid < 24576) {
    int b2 = bid - 8192;
    int half = b2 >> 13;
    int r = b2 & 8191;
    const float* s = half ? w3 : w1;
    int dr = ((r >> 4) << 5) + (r & 15) + (half << 4);
    *(u16x8*)&W13b[(size_t)dr * 2048 + t * 8] =
        cvt_row8(s + (size_t)r * 2048 + t * 8);
  } else {
    size_t i = ((size_t)(bid - 24576) * 256 + t) * 8;
    *(u16x8*)&W2b[i] = cvt_row8(&w2[i]);
  }
}

// ---------------- RMSNorm (fp32 in, bf16 out) ----------------
__global__ __launch_bounds__(256) void rmsnorm_k(const float* __restrict__ X,
                                                 const float* __restrict__ W,
                                                 u16* __restrict__ O) {
  const int row = blockIdx.x;
  const int tid = threadIdx.x;
  const float* x = X + (size_t)row * 2048;
  float4 v0 = *(const float4*)&x[tid * 8];
  float4 v1 = *(const float4*)&x[tid * 8 + 4];
  float s = v0.x * v0.x + v0.y * v0.y + v0.z * v0.z + v0.w * v0.w
          + v1.x * v1.x + v1.y * v1.y + v1.z * v1.z + v1.w * v1.w;
  #pragma unroll
  for (int m = 1; m < 64; m <<= 1) s += __shfl_xor(s, m);
  __shared__ float red[4];
  if ((tid & 63) == 0) red[tid >> 6] = s;
  __syncthreads();
  float tot = red[0] + red[1] + red[2] + red[3];
  float r = rsqrtf(tot * (1.0f / 2048.0f) + 1e-6f);
  float4 w0 = *(const float4*)&W[tid * 8];
  float4 w1 = *(const float4*)&W[tid * 8 + 4];
  u16x8 o;
  o[0] = f2bf(v0.x * r * w0.x); o[1] = f2bf(v0.y * r * w0.y);
  o[2] = f2bf(v0.z * r * w0.z); o[3] = f2bf(v0.w * r * w0.w);
  o[4] = f2bf(v1.x * r * w1.x); o[5] = f2bf(v1.y * r * w1.y);
  o[6] = f2bf(v1.z * r * w1.z); o[7] = f2bf(v1.w * r * w1.w);
  *(u16x8*)&O[(size_t)row * 2048 + tid * 8] = o;
}

// ---------------- 128^2 GEMM (wo split-K) ----------------
#define EPI_F32 0
#define EPI_ADDF32 1
#define EPI_SWIGLU 2
#define EPI_BF16G 3

template <int EPI>
__global__ __launch_bounds__(256) void gemm_bt(const u16* __restrict__ A,
                                               const u16* __restrict__ B,
                                               float* __restrict__ Cf,
                                               u16* __restrict__ Cb,
                                               const float* __restrict__ R,
                                               int M, int N, int Kt,
                                               int lda, int ldb) {
  __shared__ __align__(16) u16 As[2][128 * 32];
  __shared__ __align__(16) u16 Bs[2][128 * 32];
  const int tid = threadIdx.x;
  const int lane = tid & 63;
  const int w = tid >> 6;
  const int wm = w >> 1, wn = w & 1;
  const int m0 = blockIdx.y * 128, n0 = blockIdx.x * 128;
  const int z = blockIdx.z;
  A += (size_t)z * Kt;
  B += (size_t)z * Kt;
  Cf += (size_t)z * M * N;
  const int r0 = tid >> 2;
  const int c0 = (tid & 3) * 8;
  const int r1 = r0 + 64;
  const int laneM = lane & 15;
  const int laneK = (lane >> 4) * 8;

  f32x4 acc[4][4];
  #pragma unroll
  for (int i = 0; i < 4; i++)
    #pragma unroll
    for (int j = 0; j < 4; j++) acc[i][j] = (f32x4){0.f, 0.f, 0.f, 0.f};

  const u16* Ar0 = &A[(size_t)(m0 + r0) * lda + c0];
  const u16* Ar1 = &A[(size_t)(m0 + r1) * lda + c0];
  const u16* Br0 = &B[(size_t)(n0 + r0) * ldb + c0];
  const u16* Br1 = &B[(size_t)(n0 + r1) * ldb + c0];
  const int lofs0 = r0 * 32 + c0;
  const int lofs1 = r1 * 32 + c0;

  auto stage = [&](int bsel, int kt) {
    gload_lds16(Ar0 + kt, &As[bsel][lofs0]);
    gload_lds16(Ar1 + kt, &As[bsel][lofs1]);
    gload_lds16(Br0 + kt, &Bs[bsel][lofs0]);
    gload_lds16(Br1 + kt, &Bs[bsel][lofs1]);
  };

  stage(0, 0);
  const int nt = Kt >> 5;
  for (int t = 0; t < nt; t++) {
    const int cur = t & 1;
    if (t + 1 < nt) {
      stage(cur ^ 1, (t + 1) << 5);
      asm volatile("s_waitcnt vmcnt(4)" ::: "memory");
    } else {
      asm volatile("s_waitcnt vmcnt(0)" ::: "memory");
    }
    __builtin_amdgcn_s_barrier();
    f32x4 af[4], bfr[4];
    #pragma unroll
    for (int mi = 0; mi < 4; mi++)
      af[mi] = *(const f32x4*)&As[cur][(wm * 64 + mi * 16 + laneM) * 32 + laneK];
    #pragma unroll
    for (int ni = 0; ni < 4; ni++)
      bfr[ni] = *(const f32x4*)&Bs[cur][(wn * 64 + ni * 16 + laneM) * 32 + laneK];
    #pragma unroll
    for (int mi = 0; mi < 4; mi++)
      #pragma unroll
      for (int ni = 0; ni < 4; ni++)
        mfma_bf16_16x16x32(acc[mi][ni], af[mi], bfr[ni]);
    __builtin_amdgcn_s_barrier();
  }

  const int rowb = (lane >> 4) * 4;
  const int coll = lane & 15;
  #pragma unroll
  for (int mi = 0; mi < 4; mi++) {
    #pragma unroll
    for (int i = 0; i < 4; i++) {
      int row = m0 + wm * 64 + mi * 16 + rowb + i;
      #pragma unroll
      for (int ni = 0; ni < 4; ni++) {
        int col = n0 + wn * 64 + ni * 16 + coll;
        size_t idx = (size_t)row * N + col;
        float v = acc[mi][ni][i];
        if constexpr (EPI == EPI_F32) Cf[idx] = v;
        else Cf[idx] = v + R[idx];
      }
    }
  }
}

// ---------------- 256^2 GEMM, counted-lgkmcnt pipelined 2-block body ------
// R13 sync skeleton (vmcnt(4)-counted staging, 2 tile-boundary barriers,
// setprio, pinned order) with ONE change: all 24 ds_reads issue up front
// (bg 8, af0 8 | sched_barrier | af1 8), then lgkmcnt(8) -> MFMA0 runs while
// af1's reads drain; lgkmcnt(0) -> MFMA1.  Mid-phase barrier removed (af1
// reads the same already-validated buffer).  DS completes in-order, so
// "8 outstanding" = af1 exactly.  NOTE: requires spill-free loop (R14).
template <int EPI>
__global__ __launch_bounds__(512, 2) void gemm256(const u16* __restrict__ A,
                                                  const u16* __restrict__ B,
                                                  float* __restrict__ Cf,
                                                  u16* __restrict__ Cb,
                                                  int M, int N, int Kt,
                                                  int lda, int ldb) {
  __shared__ __align__(16) char sm[131072];
  const int tid = threadIdx.x;
  const int lane = tid & 63, w = tid >> 6;
  const int wr = w >> 2, wc = w & 3;
  const int laneM = lane & 15, laneG = lane >> 4;
  const int m0 = blockIdx.y * 256, n0 = blockIdx.x * 256;
  const int z = blockIdx.z;
  A += (size_t)z * Kt;
  B += (size_t)z * Kt;
  Cf += (size_t)z * M * N;

  const int srow = tid >> 3;        // 0..63
  const int scb = (tid & 7) * 16;   // staging col-byte 0..112

  f32x4 acc[8][4];
  #pragma unroll
  for (int i = 0; i < 8; i++)
    #pragma unroll
    for (int j = 0; j < 4; j++) acc[i][j] = (f32x4){0.f, 0.f, 0.f, 0.f};

  auto stage = [&](int buf, int ktE, int ht) {
    const int half = ht & 1;
    const bool isA = ht < 2;
    char* base = sm + (isA ? 0 : 65536) + buf * 32768 + half * 16384;
    const u16* src = isA ? A : B;
    const int ld = isA ? lda : ldb;
    const int rb = (isA ? m0 : n0) + half * 128;
    #pragma unroll
    for (int j = 0; j < 2; j++) {
      int row = j * 64 + srow;
      int scol = (scb ^ ((row & 7) << 4)) >> 1;
      gload_lds16(src + (size_t)(rb + row) * ld + ktE + scol,
                  base + j * 8192 + tid * 16);
    }
  };

  const int nkt = Kt >> 6;
  #pragma unroll
  for (int ht = 0; ht < 4; ht++) stage(0, 0, ht);

  const int bHalf = wc >> 1;           // this wave's B half
  const int bRow0 = (wc & 1) * 64;     // local row base in that half

  for (int t = 0; t < nkt; t++) {
    const int cb_ = t & 1;
    char* aBase = sm + cb_ * 32768 + wr * 16384;
    char* bBase = sm + 65536 + cb_ * 32768 + bHalf * 16384;
    const bool pre = (t + 1 < nkt);
    const int ktE1 = (t + 1) << 6;

    // stage A halves of t+1; validate tile t (counted vmcnt)
    if (pre) { stage(cb_ ^ 1, ktE1, 0); stage(cb_ ^ 1, ktE1, 1); }
    if (pre) asm volatile("s_waitcnt vmcnt(4)" ::: "memory");
    else     asm volatile("s_waitcnt vmcnt(0)" ::: "memory");
    __builtin_amdgcn_s_barrier();  // cross-wave DMA visibility for tile t

    // ---- issue ALL fragment reads: bg(8), af0(8) | fence | af1(8) ----
    f32x4 af0[4][2], af1[4][2], bg[4][2];
    #pragma unroll
    for (int ni = 0; ni < 4; ni++)
      #pragma unroll
      for (int ks = 0; ks < 2; ks++) {
        int r = bRow0 + ni * 16 + laneM;
        int cbv = ks * 64 + laneG * 16;
        bg[ni][ks] = *(const f32x4*)(bBase + r * 128 + (cbv ^ ((r & 7) << 4)));
      }
    #pragma unroll
    for (int mi = 0; mi < 4; mi++)
      #pragma unroll
      for (int ks = 0; ks < 2; ks++) {
        int r = mi * 16 + laneM;
        int cbv = ks * 64 + laneG * 16;
        af0[mi][ks] = *(const f32x4*)(aBase + r * 128 + (cbv ^ ((r & 7) << 4)));
      }
    __builtin_amdgcn_sched_barrier(0);  // pin: af1 reads issue AFTER bg/af0
    #pragma unroll
    for (int mi = 0; mi < 4; mi++)
      #pragma unroll
      for (int ks = 0; ks < 2; ks++) {
        int r = (4 + mi) * 16 + laneM;
        int cbv = ks * 64 + laneG * 16;
        af1[mi][ks] = *(const f32x4*)(aBase + r * 128 + (cbv ^ ((r & 7) << 4)));
      }
    // bg+af0 landed; af1's 8 reads drain under MFMA0
    asm volatile("s_waitcnt lgkmcnt(8)" ::: "memory");
    __builtin_amdgcn_sched_barrier(0);
    __builtin_amdgcn_s_setprio(1);
    #pragma unroll
    for (int mi = 0; mi < 4; mi++)
      #pragma unroll
      for (int ni = 0; ni < 4; ni++)
        #pragma unroll
        for (int ks = 0; ks < 2; ks++)
          mfma_bf16_16x16x32(acc[mi][ni], af0[mi][ks], bg[ni][ks]);
    __builtin_amdgcn_s_setprio(0);
    __builtin_amdgcn_sched_barrier(0);

    // stage B halves of t+1 (VMEM, doesn't touch lgkm)
    if (pre) { stage(cb_ ^ 1, ktE1, 2); stage(cb_ ^ 1, ktE1, 3); }
    asm volatile("s_waitcnt lgkmcnt(0)" ::: "memory");
    __builtin_amdgcn_sched_barrier(0);
    __builtin_amdgcn_s_setprio(1);
    #pragma unroll
    for (int mi = 0; mi < 4; mi++)
      #pragma unroll
      for (int ni = 0; ni < 4; ni++)
        #pragma unroll
        for (int ks = 0; ks < 2; ks++)
          mfma_bf16_16x16x32(acc[4 + mi][ni], af1[mi][ks], bg[ni][ks]);
    __builtin_amdgcn_s_setprio(0);
    __builtin_amdgcn_sched_barrier(0);
    __builtin_amdgcn_s_barrier();  // all reads of buf cb_ done before overwrite
  }

  // ---- epilogue ----
  #pragma unroll
  for (int mi = 0; mi < 8; mi++) {
    #pragma unroll
    for (int i = 0; i < 4; i++) {
      int row = m0 + wr * 128 + mi * 16 + laneG * 4 + i;
      if constexpr (EPI == EPI_SWIGLU) {
        #pragma unroll
        for (int np = 0; np < 2; np++) {
          float g = acc[mi][np * 2][i];
          float u = acc[mi][np * 2 + 1][i];
          float sg = g / (1.0f + __expf(-g));
          int j = (n0 >> 1) + wc * 32 + np * 16 + laneM;
          Cb[(size_t)row * (N >> 1) + j] = f2bf(sg * u);
        }
      } else if constexpr (EPI == EPI_BF16G) {
        #pragma unroll
        for (int ni = 0; ni < 4; ni++) {
          int col = n0 + wc * 64 + ni * 16 + laneM;
          Cb[(size_t)row * N + col] = f2bf(acc[mi][ni][i]);
        }
      } else {
        #pragma unroll
        for (int ni = 0; ni < 4; ni++) {
          int col = n0 + wc * 64 + ni * 16 + laneM;
          Cf[(size_t)row * N + col] = acc[mi][ni][i];
        }
      }
    }
  }
}

// ---------------- split-K reduces ----------------
__global__ __launch_bounds__(256) void reduce5_k(const float* __restrict__ P,
                                                 const float* __restrict__ H,
                                                 float* __restrict__ out) {
  size_t i = ((size_t)blockIdx.x * 256 + threadIdx.x) * 4;
  const size_t MN = 4194304;
  float4 a = *(const float4*)&P[i];
  float4 b = *(const float4*)&P[MN + i];
  float4 c = *(const float4*)&P[2 * MN + i];
  float4 d = *(const float4*)&P[3 * MN + i];
  float4 h = *(const float4*)&H[i];
  float4 o;
  o.x = a.x + b.x + c.x + d.x + h.x;
  o.y = a.y + b.y + c.y + d.y + h.y;
  o.z = a.z + b.z + c.z + d.z + h.z;
  o.w = a.w + b.w + c.w + d.w + h.w;
  *(float4*)&out[i] = o;
}

// wo split-K2: H = P0 + P1 + x (residual)
__global__ __launch_bounds__(256) void reduce3_k(const float* __restrict__ P,
                                                 const float* __restrict__ X,
                                                 float* __restrict__ H) {
  size_t i = ((size_t)blockIdx.x * 256 + threadIdx.x) * 4;
  const size_t MN = 4194304;
  float4 a = *(const float4*)&P[i];
  float4 b = *(const float4*)&P[MN + i];
  float4 h = *(const float4*)&X[i];
  float4 o;
  o.x = a.x + b.x + h.x;
  o.y = a.y + b.y + h.y;
  o.z = a.z + b.z + h.z;
  o.w = a.w + b.w + h.w;
  *(float4*)&H[i] = o;
}

// ---------------- RoPE + Qe/Ke build + V transpose (bf16 QKV input) -------
__device__ __forceinline__ void rope_row(const u16* __restrict__ src,
                                         u16* __restrict__ dst, int s, int q4) {
  float vv[32];
  #pragma unroll
  for (int t = 0; t < 4; t++) {
    u16x8 v = *(const u16x8*)&src[t * 8];
    #pragma unroll
    for (int j = 0; j < 8; j++) vv[t * 8 + j] = bf2f(v[j]);
  }
  u16 o1[32], o2[32];
  #pragma unroll
  for (int jl = 0; jl < 16; jl++) {
    int j = q4 * 16 + jl;
    float inv = exp2f(-(float)j * 0.20762050593046014f); // log2(10000)/64
    float ang = (float)s * inv;
    float sn, cs;
    __sincosf(ang, &sn, &cs);
    float a = vv[2 * jl], b = vv[2 * jl + 1];
    float r1 = a * cs - b * sn;
    float r2 = a * sn + b * cs;
    o1[2 * jl] = f2bf(r1);
    o1[2 * jl + 1] = f2bf(r2);
    o2[2 * jl] = f2bf(0.31622776601683794f * r1 * r1);  // sqrt(LAM)*x^2
    o2[2 * jl + 1] = f2bf(0.31622776601683794f * r2 * r2);
  }
  #pragma unroll
  for (int t = 0; t < 4; t++) {
    *(u16x8*)&dst[q4 * 32 + t * 8] = *(const u16x8*)&o1[t * 8];
    *(u16x8*)&dst[128 + q4 * 32 + t * 8] = *(const u16x8*)&o2[t * 8];
  }
}

__global__ __launch_bounds__(256) void qkv_post_k(const u16* __restrict__ QKVB,
                                                  u16* __restrict__ Qe,
                                                  u16* __restrict__ Ke,
                                                  u16* __restrict__ Vt) {
  const int st = blockIdx.x;  // 0..15
  const int bh = blockIdx.y;  // 0..31
  const int b = bh >> 4, h = bh & 15;
  const int tid = threadIdx.x;
  {
    int r = tid >> 2, q4 = tid & 3;
    int s = st * 64 + r;
    size_t rowin = ((size_t)b * 1024 + s) * 6144 + h * 128 + q4 * 32;
    size_t rowe = ((size_t)bh * 1024 + s) * 256;
    rope_row(QKVB + rowin, Qe + rowe, s, q4);
    rope_row(QKVB + rowin + 2048, Ke + rowe, s, q4);
  }
  __shared__ __align__(16) u16 vts[128 * 72];
  {
    int r = tid >> 2, q4 = tid & 3;
    int s = st * 64 + r;
    const u16* src = QKVB + ((size_t)b * 1024 + s) * 6144 + 4096 + h * 128 + q4 * 32;
    #pragma unroll
    for (int k = 0; k < 32; k += 8) {
      u16x8 v = *(const u16x8*)&src[k];
      int d = q4 * 32 + k;
      #pragma unroll
      for (int j = 0; j < 8; j++) vts[(d + j) * 72 + r] = v[j];
    }
  }
  __syncthreads();
  {
    int d = tid >> 1, sp = (tid & 1) * 32;
    u16* dst = Vt + ((size_t)bh * 128 + d) * 1024 + st * 64 + sp;
    #pragma unroll
    for (int k = 0; k < 32; k += 8)
      *(u16x8*)&dst[k] = *(const u16x8*)&vts[d * 72 + sp + k];
  }
}

// ---------------- Flash attention (unchanged, verified) ----------------
__global__ __launch_bounds__(256, 2) void attn_k(const u16* __restrict__ Qe,
                                                 const u16* __restrict__ Ke,
                                                 const u16* __restrict__ Vt,
                                                 u16* __restrict__ AO) {
  const int bh = blockIdx.x;  // 0..31
  const int qt = blockIdx.y;  // 0..15
  const int b = bh >> 4, h = bh & 15;
  const int tid = threadIdx.x;
  const int w = tid >> 6, lane = tid & 63;
  const int laneM = lane & 15, laneG = lane >> 4;

  __shared__ __align__(16) char smem[57344];
  u16* plu = (u16*)(smem + 49152 + w * 2048);

  const char* KeB = (const char*)Ke + (size_t)bh * 524288;
  const char* VtB = (const char*)Vt + (size_t)bh * 262144;

  const size_t qbase = ((size_t)bh * 1024 + qt * 64 + w * 16 + laneM) * 256 + laneG * 8;
  f32x4 qf[8];
  #pragma unroll
  for (int kk = 0; kk < 8; kk++) qf[kk] = *(const f32x4*)&Qe[qbase + kk * 32];

  float m_i[4], l_i[4];
  #pragma unroll
  for (int i = 0; i < 4; i++) { m_i[i] = -1e30f; l_i[i] = 0.f; }
  f32x4 accO[8];
  #pragma unroll
  for (int n = 0; n < 8; n++) accO[n] = (f32x4){0.f, 0.f, 0.f, 0.f};

  u16x8 kreg[4], vreg[2];
  auto loadRegs = [&](int ktn) {
    const char* ks = KeB + (size_t)ktn * 16384;
    #pragma unroll
    for (int j = 0; j < 4; j++) {
      int p = j * 4096 + tid * 16;
      kreg[j] = *(const u16x8*)(ks + p);
    }
    const char* vs = VtB + (size_t)ktn * 64;
    #pragma unroll
    for (int j = 0; j < 2; j++) {
      int p = j * 4096 + tid * 16;
      int r = p >> 6, x = p & 63;
      vreg[j] = *(const u16x8*)(vs + (size_t)r * 2048 + x);
    }
  };
  auto writeLDS = [&](int bsel) {
    char* kd = smem + (bsel ? 16384 : 0);
    #pragma unroll
    for (int j = 0; j < 4; j++) {
      int p = j * 4096 + tid * 16;
      int r = p >> 9, x = p & 511;
      *(u16x8*)(kd + r * 512 + (x ^ ((r & 7) << 4))) = kreg[j];
    }
    char* vd = smem + 32768 + (bsel ? 8192 : 0);
    #pragma unroll
    for (int j = 0; j < 2; j++) {
      int p = j * 4096 + tid * 16;
      int r = p >> 6, x = p & 63;
      *(u16x8*)(vd + r * 64 + (x ^ (((r >> 1) & 3) << 4))) = vreg[j];
    }
  };

  loadRegs(0);
  writeLDS(0);
  int cur = 0;
  const float scale = 0.08838834764831845f;

  for (int kt = 0; kt < 32; kt++) {
    if (kt < 31) loadRegs(kt + 1);
    __syncthreads();
    const char* Kc = smem + (cur ? 16384 : 0);
    const char* Vc = smem + 32768 + (cur ? 8192 : 0);

    f32x4 accS[2];
    #pragma unroll
    for (int n = 0; n < 2; n++) accS[n] = (f32x4){0.f, 0.f, 0.f, 0.f};
    #pragma unroll
    for (int n = 0; n < 2; n++) {
      int r = n * 16 + laneM;
      const char* krow = Kc + r * 512;
      int sw = (r & 7) << 4;
      #pragma unroll
      for (int kk = 0; kk < 8; kk++) {
        f32x4 kf = *(const f32x4*)(krow + ((kk * 64 + laneG * 16) ^ sw));
        mfma_bf16_16x16x32(accS[n], qf[kk], kf);
      }
    }

    float p[2][4], sf[4];
    #pragma unroll
    for (int i = 0; i < 4; i++) {
      float mx = fmaxf(accS[0][i], accS[1][i]) * scale;
      #pragma unroll
      for (int m = 1; m < 16; m <<= 1) mx = fmaxf(mx, __shfl_xor(mx, m));
      float mnew = fmaxf(m_i[i], mx);
      sf[i] = __expf(m_i[i] - mnew);
      m_i[i] = mnew;
      float p0 = __expf(accS[0][i] * scale - mnew);
      float p1 = __expf(accS[1][i] * scale - mnew);
      p[0][i] = p0; p[1][i] = p1;
      float rs = p0 + p1;
      #pragma unroll
      for (int m = 1; m < 16; m <<= 1) rs += __shfl_xor(rs, m);
      l_i[i] = l_i[i] * sf[i] + rs;
    }
    #pragma unroll
    for (int n = 0; n < 8; n++) {
      accO[n][0] *= sf[0]; accO[n][1] *= sf[1];
      accO[n][2] *= sf[2]; accO[n][3] *= sf[3];
    }

    #pragma unroll
    for (int n = 0; n < 2; n++)
      #pragma unroll
      for (int i = 0; i < 4; i++) {
        int row = laneG * 4 + i;
        int col = n * 16 + laneM;
        plu[row * 64 + (col ^ (((row >> 2) & 3) << 4))] = f2bf(p[n][i]);
      }
    f32x4 pa = *(const f32x4*)&plu[laneM * 64 +
                                   ((laneG * 8) ^ (((laneM >> 2) & 3) << 4))];

    #pragma unroll
    for (int n = 0; n < 8; n++) {
      int r = n * 16 + laneM;
      f32x4 vf = *(const f32x4*)(Vc + r * 64 + ((laneG * 16) ^ (((r >> 1) & 3) << 4)));
      mfma_bf16_16x16x32(accO[n], pa, vf);
    }

    if (kt < 31) writeLDS(cur ^ 1);
    cur ^= 1;
  }

  #pragma unroll
  for (int i = 0; i < 4; i++) {
    float inv_l = 1.f / l_i[i];
    int row = b * 1024 + qt * 64 + w * 16 + laneG * 4 + i;
    #pragma unroll
    for (int n = 0; n < 8; n++) {
      float o = accO[n][i] * inv_l;
      o = o + 0.05f * o * o;  // gate collapses (out2==out1); HAD term
      AO[(size_t)row * 2048 + h * 128 + n * 16 + laneM] = f2bf(o);
    }
  }
}

// ---------------- launch ----------------
extern "C" void kernel_launch(void* const* d_in, const int* in_sizes, int n_in,
                              void* d_out, int out_size, void* d_ws, size_t ws_size,
                              hipStream_t stream) {
  const float* x   = (const float*)d_in[0];
  const float* n1w = (const float*)d_in[1];
  const float* n2w = (const float*)d_in[2];
  const float* wq  = (const float*)d_in[3];
  const float* wk  = (const float*)d_in[4];
  const float* wv  = (const float*)d_in[5];
  const float* wo  = (const float*)d_in[6];
  const float* w1  = (const float*)d_in[8];
  const float* w3  = (const float*)d_in[9];
  const float* w2  = (const float*)d_in[10];

  char* ws = (char*)d_ws;
  u16* WQKVb = (u16*)(ws + 0);          // [8192][2048] bf16 (q|k|v|o)
  u16* WOb   = (u16*)(ws + 25165824);   // rows 6144..8191 of cvt dst
  u16* W13b  = (u16*)(ws + 33554432);   // [16384][2048] interleaved, 67 MB
  u16* W2b   = (u16*)(ws + 100663296);  // [2048][8192], 33.6 MB
  u16* XN    = (u16*)(ws + 134217728);  // 8.4 MB (reused for HN)
  u16* QKVB  = (u16*)(ws + 142606336);  // [2048][6144] bf16, 25.2 MB
  u16* U     = (u16*)(ws + 142606336);  // [2048][8192] bf16 (reuses QKVB region)
  float* P   = (float*)(ws + 176160768); // 4x [2048][2048] f32 = 67 MB
  u16* QE    = (u16*)(ws + 192937984);  // 16.8 MB
  u16* KE    = (u16*)(ws + 209715200);  // 16.8 MB
  u16* VT    = (u16*)(ws + 226492416);  // 8.4 MB
  u16* AO    = (u16*)(ws + 234881024);  // 8.4 MB
  float* H   = (float*)(ws + 243269632); // 16.8 MB, ends 260046848

  // all weight conversions in ONE dispatch
  cvt_all<<<32768, 256, 0, stream>>>(wq, wk, wv, wo, w1, w3, w2,
                                     WQKVb, W13b, W2b);

  rmsnorm_k<<<2048, 256, 0, stream>>>(x, n1w, XN);

  // fused QKV: [2048,2048] x [6144,2048]^T -> QKVB bf16   (256^2)
  gemm256<EPI_BF16G><<<dim3(24, 8), 512, 0, stream>>>(
      XN, WQKVb, nullptr, QKVB, 2048, 6144, 2048, 2048, 2048);

  qkv_post_k<<<dim3(16, 32), 256, 0, stream>>>(QKVB, QE, KE, VT);

  attn_k<<<dim3(32, 16), 256, 0, stream>>>(QE, KE, VT, AO);

  // wo split-K=2 -> P[0..1], then H = P0+P1+x   (128^2)
  gemm_bt<EPI_F32><<<dim3(16, 16, 2), 256, 0, stream>>>(
      AO, WOb, P, nullptr, nullptr, 2048, 2048, 1024, 2048, 2048);
  reduce3_k<<<4096, 256, 0, stream>>>(P, x, H);

  rmsnorm_k<<<2048, 256, 0, stream>>>(H, n2w, XN);

  // fused w1|w3 + swiglu -> U bf16 [2048][8192]   (256^2)
  gemm256<EPI_SWIGLU><<<dim3(64, 8), 512, 0, stream>>>(
      XN, W13b, nullptr, U, 2048, 16384, 2048, 2048, 2048);

  // w2 split-K=4 -> partials P[z]   (256^2)
  gemm256<EPI_F32><<<dim3(8, 8, 4), 512, 0, stream>>>(
      U, W2b, P, nullptr, 2048, 2048, 2048, 8192, 8192);

  // out = sum(P) + H
  reduce5_k<<<4096, 256, 0, stream>>>(P, H, (float*)d_out);
}

// Round 17
// 468.074 us; speedup vs baseline: 1.0216x; 1.0216x over previous
//
#include <hip/hip_runtime.h>
#include <hip/hip_bf16.h>

typedef unsigned short u16;
typedef unsigned int u32;
typedef u16 u16x8 __attribute__((ext_vector_type(8)));
typedef float f32x4 __attribute__((ext_vector_type(4)));

__device__ __forceinline__ u16 f2bf(float f) {
  union { float f; u32 u; } v; v.f = f;
  u32 r = v.u + 0x7FFFu + ((v.u >> 16) & 1u);
  return (u16)(r >> 16);
}
__device__ __forceinline__ float bf2f(u16 h) {
  union { u32 u; float f; } v; v.u = ((u32)h) << 16;
  return v.f;
}
__device__ __forceinline__ void mfma_bf16_16x16x32(f32x4& acc, const f32x4& a, const f32x4& b) {
  asm("v_mfma_f32_16x16x32_bf16 %0, %1, %2, %0" : "+v"(acc) : "v"(a), "v"(b));
}
__device__ __forceinline__ void gload_lds16(const void* g, void* l) {
  __builtin_amdgcn_global_load_lds(
      (const __attribute__((address_space(1))) unsigned int*)g,
      (__attribute__((address_space(3))) unsigned int*)l, 16, 0, 0);
}

// ---------------- fp32 -> bf16 weight converts (ONE dispatch) -------------
__device__ __forceinline__ u16x8 cvt_row8(const float* p) {
  float4 f0 = *(const float4*)p;
  float4 f1 = *(const float4*)(p + 4);
  u16x8 o;
  o[0] = f2bf(f0.x); o[1] = f2bf(f0.y); o[2] = f2bf(f0.z); o[3] = f2bf(f0.w);
  o[4] = f2bf(f1.x); o[5] = f2bf(f1.y); o[6] = f2bf(f1.z); o[7] = f2bf(f1.w);
  return o;
}

__global__ __launch_bounds__(256) void cvt_all(
    const float* __restrict__ wq, const float* __restrict__ wk,
    const float* __restrict__ wv, const float* __restrict__ wo,
    const float* __restrict__ w1, const float* __restrict__ w3,
    const float* __restrict__ w2, u16* __restrict__ WQKVb,
    u16* __restrict__ W13b, u16* __restrict__ W2b) {
  int bid = blockIdx.x;
  int t = threadIdx.x;
  if (bid < 8192) {
    const float* s = (bid < 2048) ? wq : (bid < 4096) ? wk : (bid < 6144) ? wv : wo;
    int r = bid & 2047;
    *(u16x8*)&WQKVb[(size_t)bid * 2048 + t * 8] =
        cvt_row8(s + (size_t)r * 2048 + t * 8);
  } else if (bid < 24576) {
    int b2 = bid - 8192;
    int half = b2 >> 13;
    int r = b2 & 8191;
    const float* s = half ? w3 : w1;
    int dr = ((r >> 4) << 5) + (r & 15) + (half << 4);
    *(u16x8*)&W13b[(size_t)dr * 2048 + t * 8] =
        cvt_row8(s + (size_t)r * 2048 + t * 8);
  } else {
    size_t i = ((size_t)(bid - 24576) * 256 + t) * 8;
    *(u16x8*)&W2b[i] = cvt_row8(&w2[i]);
  }
}

// ---------------- RMSNorm (fp32 in, bf16 out) ----------------
__global__ __launch_bounds__(256) void rmsnorm_k(const float* __restrict__ X,
                                                 const float* __restrict__ W,
                                                 u16* __restrict__ O) {
  const int row = blockIdx.x;
  const int tid = threadIdx.x;
  const float* x = X + (size_t)row * 2048;
  float4 v0 = *(const float4*)&x[tid * 8];
  float4 v1 = *(const float4*)&x[tid * 8 + 4];
  float s = v0.x * v0.x + v0.y * v0.y + v0.z * v0.z + v0.w * v0.w
          + v1.x * v1.x + v1.y * v1.y + v1.z * v1.z + v1.w * v1.w;
  #pragma unroll
  for (int m = 1; m < 64; m <<= 1) s += __shfl_xor(s, m);
  __shared__ float red[4];
  if ((tid & 63) == 0) red[tid >> 6] = s;
  __syncthreads();
  float tot = red[0] + red[1] + red[2] + red[3];
  float r = rsqrtf(tot * (1.0f / 2048.0f) + 1e-6f);
  float4 w0 = *(const float4*)&W[tid * 8];
  float4 w1 = *(const float4*)&W[tid * 8 + 4];
  u16x8 o;
  o[0] = f2bf(v0.x * r * w0.x); o[1] = f2bf(v0.y * r * w0.y);
  o[2] = f2bf(v0.z * r * w0.z); o[3] = f2bf(v0.w * r * w0.w);
  o[4] = f2bf(v1.x * r * w1.x); o[5] = f2bf(v1.y * r * w1.y);
  o[6] = f2bf(v1.z * r * w1.z); o[7] = f2bf(v1.w * r * w1.w);
  *(u16x8*)&O[(size_t)row * 2048 + tid * 8] = o;
}

// ---- fused: H = P0+P1+x (row), then XN = rmsnorm(H)*w (bf16) ------------
__global__ __launch_bounds__(256) void add_rmsnorm_k(const float* __restrict__ P,
                                                     const float* __restrict__ X,
                                                     const float* __restrict__ W,
                                                     float* __restrict__ H,
                                                     u16* __restrict__ O) {
  const int row = blockIdx.x;
  const int tid = threadIdx.x;
  const size_t MN = 4194304;
  size_t base = (size_t)row * 2048 + tid * 8;
  float4 a0 = *(const float4*)&P[base];
  float4 a1 = *(const float4*)&P[base + 4];
  float4 b0 = *(const float4*)&P[MN + base];
  float4 b1 = *(const float4*)&P[MN + base + 4];
  float4 x0 = *(const float4*)&X[base];
  float4 x1 = *(const float4*)&X[base + 4];
  float4 v0, v1;
  v0.x = a0.x + b0.x + x0.x; v0.y = a0.y + b0.y + x0.y;
  v0.z = a0.z + b0.z + x0.z; v0.w = a0.w + b0.w + x0.w;
  v1.x = a1.x + b1.x + x1.x; v1.y = a1.y + b1.y + x1.y;
  v1.z = a1.z + b1.z + x1.z; v1.w = a1.w + b1.w + x1.w;
  *(float4*)&H[base] = v0;
  *(float4*)&H[base + 4] = v1;
  float s = v0.x * v0.x + v0.y * v0.y + v0.z * v0.z + v0.w * v0.w
          + v1.x * v1.x + v1.y * v1.y + v1.z * v1.z + v1.w * v1.w;
  #pragma unroll
  for (int m = 1; m < 64; m <<= 1) s += __shfl_xor(s, m);
  __shared__ float red[4];
  if ((tid & 63) == 0) red[tid >> 6] = s;
  __syncthreads();
  float tot = red[0] + red[1] + red[2] + red[3];
  float r = rsqrtf(tot * (1.0f / 2048.0f) + 1e-6f);
  float4 w0 = *(const float4*)&W[tid * 8];
  float4 w1 = *(const float4*)&W[tid * 8 + 4];
  u16x8 o;
  o[0] = f2bf(v0.x * r * w0.x); o[1] = f2bf(v0.y * r * w0.y);
  o[2] = f2bf(v0.z * r * w0.z); o[3] = f2bf(v0.w * r * w0.w);
  o[4] = f2bf(v1.x * r * w1.x); o[5] = f2bf(v1.y * r * w1.y);
  o[6] = f2bf(v1.z * r * w1.z); o[7] = f2bf(v1.w * r * w1.w);
  *(u16x8*)&O[(size_t)row * 2048 + tid * 8] = o;
}

// ---------------- 128^2 GEMM (wo split-K) ----------------
#define EPI_F32 0
#define EPI_ADDF32 1
#define EPI_SWIGLU 2
#define EPI_BF16G 3

template <int EPI>
__global__ __launch_bounds__(256) void gemm_bt(const u16* __restrict__ A,
                                               const u16* __restrict__ B,
                                               float* __restrict__ Cf,
                                               u16* __restrict__ Cb,
                                               const float* __restrict__ R,
                                               int M, int N, int Kt,
                                               int lda, int ldb) {
  __shared__ __align__(16) u16 As[2][128 * 32];
  __shared__ __align__(16) u16 Bs[2][128 * 32];
  const int tid = threadIdx.x;
  const int lane = tid & 63;
  const int w = tid >> 6;
  const int wm = w >> 1, wn = w & 1;
  const int m0 = blockIdx.y * 128, n0 = blockIdx.x * 128;
  const int z = blockIdx.z;
  A += (size_t)z * Kt;
  B += (size_t)z * Kt;
  Cf += (size_t)z * M * N;
  const int r0 = tid >> 2;
  const int c0 = (tid & 3) * 8;
  const int r1 = r0 + 64;
  const int laneM = lane & 15;
  const int laneK = (lane >> 4) * 8;

  f32x4 acc[4][4];
  #pragma unroll
  for (int i = 0; i < 4; i++)
    #pragma unroll
    for (int j = 0; j < 4; j++) acc[i][j] = (f32x4){0.f, 0.f, 0.f, 0.f};

  const u16* Ar0 = &A[(size_t)(m0 + r0) * lda + c0];
  const u16* Ar1 = &A[(size_t)(m0 + r1) * lda + c0];
  const u16* Br0 = &B[(size_t)(n0 + r0) * ldb + c0];
  const u16* Br1 = &B[(size_t)(n0 + r1) * ldb + c0];
  const int lofs0 = r0 * 32 + c0;
  const int lofs1 = r1 * 32 + c0;

  auto stage = [&](int bsel, int kt) {
    gload_lds16(Ar0 + kt, &As[bsel][lofs0]);
    gload_lds16(Ar1 + kt, &As[bsel][lofs1]);
    gload_lds16(Br0 + kt, &Bs[bsel][lofs0]);
    gload_lds16(Br1 + kt, &Bs[bsel][lofs1]);
  };

  stage(0, 0);
  const int nt = Kt >> 5;
  for (int t = 0; t < nt; t++) {
    const int cur = t & 1;
    if (t + 1 < nt) {
      stage(cur ^ 1, (t + 1) << 5);
      asm volatile("s_waitcnt vmcnt(4)" ::: "memory");
    } else {
      asm volatile("s_waitcnt vmcnt(0)" ::: "memory");
    }
    __builtin_amdgcn_s_barrier();
    f32x4 af[4], bfr[4];
    #pragma unroll
    for (int mi = 0; mi < 4; mi++)
      af[mi] = *(const f32x4*)&As[cur][(wm * 64 + mi * 16 + laneM) * 32 + laneK];
    #pragma unroll
    for (int ni = 0; ni < 4; ni++)
      bfr[ni] = *(const f32x4*)&Bs[cur][(wn * 64 + ni * 16 + laneM) * 32 + laneK];
    #pragma unroll
    for (int mi = 0; mi < 4; mi++)
      #pragma unroll
      for (int ni = 0; ni < 4; ni++)
        mfma_bf16_16x16x32(acc[mi][ni], af[mi], bfr[ni]);
    __builtin_amdgcn_s_barrier();
  }

  const int rowb = (lane >> 4) * 4;
  const int coll = lane & 15;
  #pragma unroll
  for (int mi = 0; mi < 4; mi++) {
    #pragma unroll
    for (int i = 0; i < 4; i++) {
      int row = m0 + wm * 64 + mi * 16 + rowb + i;
      #pragma unroll
      for (int ni = 0; ni < 4; ni++) {
        int col = n0 + wn * 64 + ni * 16 + coll;
        size_t idx = (size_t)row * N + col;
        float v = acc[mi][ni][i];
        if constexpr (EPI == EPI_F32) Cf[idx] = v;
        else Cf[idx] = v + R[idx];
      }
    }
  }
}

// ---------------- 256^2 GEMM, 2 balanced phases, B register-resident ------
// R13/R15-verified body (128.5us w1w3, MfmaUtil 46, VGPR 112, no spills).
// Counted vmcnt requires a spill-free K-loop (R14); pinned lgkmcnt(0) per
// phase beats unpinned (~8%, R11/R12) and counted-lgkm (R16).
template <int EPI>
__global__ __launch_bounds__(512, 2) void gemm256(const u16* __restrict__ A,
                                                  const u16* __restrict__ B,
                                                  float* __restrict__ Cf,
                                                  u16* __restrict__ Cb,
                                                  int M, int N, int Kt,
                                                  int lda, int ldb) {
  __shared__ __align__(16) char sm[131072];
  const int tid = threadIdx.x;
  const int lane = tid & 63, w = tid >> 6;
  const int wr = w >> 2, wc = w & 3;
  const int laneM = lane & 15, laneG = lane >> 4;
  const int m0 = blockIdx.y * 256, n0 = blockIdx.x * 256;
  const int z = blockIdx.z;
  A += (size_t)z * Kt;
  B += (size_t)z * Kt;
  Cf += (size_t)z * M * N;

  const int srow = tid >> 3;        // 0..63
  const int scb = (tid & 7) * 16;   // staging col-byte 0..112

  f32x4 acc[8][4];
  #pragma unroll
  for (int i = 0; i < 8; i++)
    #pragma unroll
    for (int j = 0; j < 4; j++) acc[i][j] = (f32x4){0.f, 0.f, 0.f, 0.f};

  auto stage = [&](int buf, int ktE, int ht) {
    const int half = ht & 1;
    const bool isA = ht < 2;
    char* base = sm + (isA ? 0 : 65536) + buf * 32768 + half * 16384;
    const u16* src = isA ? A : B;
    const int ld = isA ? lda : ldb;
    const int rb = (isA ? m0 : n0) + half * 128;
    #pragma unroll
    for (int j = 0; j < 2; j++) {
      int row = j * 64 + srow;
      int scol = (scb ^ ((row & 7) << 4)) >> 1;
      gload_lds16(src + (size_t)(rb + row) * ld + ktE + scol,
                  base + j * 8192 + tid * 16);
    }
  };

  const int nkt = Kt >> 6;
  #pragma unroll
  for (int ht = 0; ht < 4; ht++) stage(0, 0, ht);

  const int bHalf = wc >> 1;           // this wave's B half
  const int bRow0 = (wc & 1) * 64;     // local row base in that half

  for (int t = 0; t < nkt; t++) {
    const int cb_ = t & 1;
    char* aBase = sm + cb_ * 32768 + wr * 16384;
    char* bBase = sm + 65536 + cb_ * 32768 + bHalf * 16384;
    const bool pre = (t + 1 < nkt);
    const int ktE1 = (t + 1) << 6;

    f32x4 af[4][2], bg[4][2];

    // ---- phase 0: stage A halves of t+1; validate tile t; B(all)+A(mh0) ----
    if (pre) { stage(cb_ ^ 1, ktE1, 0); stage(cb_ ^ 1, ktE1, 1); }
    if (pre) asm volatile("s_waitcnt vmcnt(4)" ::: "memory");
    else     asm volatile("s_waitcnt vmcnt(0)" ::: "memory");
    __builtin_amdgcn_s_barrier();  // cross-wave DMA visibility for tile t
    #pragma unroll
    for (int ni = 0; ni < 4; ni++)
      #pragma unroll
      for (int ks = 0; ks < 2; ks++) {
        int r = bRow0 + ni * 16 + laneM;
        int cbv = ks * 64 + laneG * 16;
        bg[ni][ks] = *(const f32x4*)(bBase + r * 128 + (cbv ^ ((r & 7) << 4)));
      }
    #pragma unroll
    for (int mi = 0; mi < 4; mi++)
      #pragma unroll
      for (int ks = 0; ks < 2; ks++) {
        int r = mi * 16 + laneM;
        int cbv = ks * 64 + laneG * 16;
        af[mi][ks] = *(const f32x4*)(aBase + r * 128 + (cbv ^ ((r & 7) << 4)));
      }
    asm volatile("s_waitcnt lgkmcnt(0)" ::: "memory");
    __builtin_amdgcn_sched_barrier(0);
    __builtin_amdgcn_s_setprio(1);
    #pragma unroll
    for (int mi = 0; mi < 4; mi++)
      #pragma unroll
      for (int ni = 0; ni < 4; ni++)
        #pragma unroll
        for (int ks = 0; ks < 2; ks++)
          mfma_bf16_16x16x32(acc[mi][ni], af[mi][ks], bg[ni][ks]);
    __builtin_amdgcn_s_setprio(0);
    __builtin_amdgcn_sched_barrier(0);

    // ---- phase 1: stage B halves of t+1; A(mh1) ----
    if (pre) { stage(cb_ ^ 1, ktE1, 2); stage(cb_ ^ 1, ktE1, 3); }
    __builtin_amdgcn_s_barrier();  // phase alignment (wave role-split)
    #pragma unroll
    for (int mi = 0; mi < 4; mi++)
      #pragma unroll
      for (int ks = 0; ks < 2; ks++) {
        int r = (4 + mi) * 16 + laneM;
        int cbv = ks * 64 + laneG * 16;
        af[mi][ks] = *(const f32x4*)(aBase + r * 128 + (cbv ^ ((r & 7) << 4)));
      }
    asm volatile("s_waitcnt lgkmcnt(0)" ::: "memory");
    __builtin_amdgcn_sched_barrier(0);
    __builtin_amdgcn_s_setprio(1);
    #pragma unroll
    for (int mi = 0; mi < 4; mi++)
      #pragma unroll
      for (int ni = 0; ni < 4; ni++)
        #pragma unroll
        for (int ks = 0; ks < 2; ks++)
          mfma_bf16_16x16x32(acc[4 + mi][ni], af[mi][ks], bg[ni][ks]);
    __builtin_amdgcn_s_setprio(0);
    __builtin_amdgcn_sched_barrier(0);
    __builtin_amdgcn_s_barrier();  // all reads of buf cb_ done before overwrite
  }

  // ---- epilogue ----
  #pragma unroll
  for (int mi = 0; mi < 8; mi++) {
    #pragma unroll
    for (int i = 0; i < 4; i++) {
      int row = m0 + wr * 128 + mi * 16 + laneG * 4 + i;
      if constexpr (EPI == EPI_SWIGLU) {
        #pragma unroll
        for (int np = 0; np < 2; np++) {
          float g = acc[mi][np * 2][i];
          float u = acc[mi][np * 2 + 1][i];
          float sg = g / (1.0f + __expf(-g));
          int j = (n0 >> 1) + wc * 32 + np * 16 + laneM;
          Cb[(size_t)row * (N >> 1) + j] = f2bf(sg * u);
        }
      } else if constexpr (EPI == EPI_BF16G) {
        #pragma unroll
        for (int ni = 0; ni < 4; ni++) {
          int col = n0 + wc * 64 + ni * 16 + laneM;
          Cb[(size_t)row * N + col] = f2bf(acc[mi][ni][i]);
        }
      } else {
        #pragma unroll
        for (int ni = 0; ni < 4; ni++) {
          int col = n0 + wc * 64 + ni * 16 + laneM;
          Cf[(size_t)row * N + col] = acc[mi][ni][i];
        }
      }
    }
  }
}

// ---------------- split-K reduce: out = P0+P1+P2+P3 + H ----------------
__global__ __launch_bounds__(256) void reduce5_k(const float* __restrict__ P,
                                                 const float* __restrict__ H,
                                                 float* __restrict__ out) {
  size_t i = ((size_t)blockIdx.x * 256 + threadIdx.x) * 4;
  const size_t MN = 4194304;
  float4 a = *(const float4*)&P[i];
  float4 b = *(const float4*)&P[MN + i];
  float4 c = *(const float4*)&P[2 * MN + i];
  float4 d = *(const float4*)&P[3 * MN + i];
  float4 h = *(const float4*)&H[i];
  float4 o;
  o.x = a.x + b.x + c.x + d.x + h.x;
  o.y = a.y + b.y + c.y + d.y + h.y;
  o.z = a.z + b.z + c.z + d.z + h.z;
  o.w = a.w + b.w + c.w + d.w + h.w;
  *(float4*)&out[i] = o;
}

// ---------------- RoPE + Qe/Ke build + V transpose (bf16 QKV input) -------
__device__ __forceinline__ void rope_row(const u16* __restrict__ src,
                                         u16* __restrict__ dst, int s, int q4) {
  float vv[32];
  #pragma unroll
  for (int t = 0; t < 4; t++) {
    u16x8 v = *(const u16x8*)&src[t * 8];
    #pragma unroll
    for (int j = 0; j < 8; j++) vv[t * 8 + j] = bf2f(v[j]);
  }
  u16 o1[32], o2[32];
  #pragma unroll
  for (int jl = 0; jl < 16; jl++) {
    int j = q4 * 16 + jl;
    float inv = exp2f(-(float)j * 0.20762050593046014f); // log2(10000)/64
    float ang = (float)s * inv;
    float sn, cs;
    __sincosf(ang, &sn, &cs);
    float a = vv[2 * jl], b = vv[2 * jl + 1];
    float r1 = a * cs - b * sn;
    float r2 = a * sn + b * cs;
    o1[2 * jl] = f2bf(r1);
    o1[2 * jl + 1] = f2bf(r2);
    o2[2 * jl] = f2bf(0.31622776601683794f * r1 * r1);  // sqrt(LAM)*x^2
    o2[2 * jl + 1] = f2bf(0.31622776601683794f * r2 * r2);
  }
  #pragma unroll
  for (int t = 0; t < 4; t++) {
    *(u16x8*)&dst[q4 * 32 + t * 8] = *(const u16x8*)&o1[t * 8];
    *(u16x8*)&dst[128 + q4 * 32 + t * 8] = *(const u16x8*)&o2[t * 8];
  }
}

__global__ __launch_bounds__(256) void qkv_post_k(const u16* __restrict__ QKVB,
                                                  u16* __restrict__ Qe,
                                                  u16* __restrict__ Ke,
                                                  u16* __restrict__ Vt) {
  const int st = blockIdx.x;  // 0..15
  const int bh = blockIdx.y;  // 0..31
  const int b = bh >> 4, h = bh & 15;
  const int tid = threadIdx.x;
  {
    int r = tid >> 2, q4 = tid & 3;
    int s = st * 64 + r;
    size_t rowin = ((size_t)b * 1024 + s) * 6144 + h * 128 + q4 * 32;
    size_t rowe = ((size_t)bh * 1024 + s) * 256;
    rope_row(QKVB + rowin, Qe + rowe, s, q4);
    rope_row(QKVB + rowin + 2048, Ke + rowe, s, q4);
  }
  __shared__ __align__(16) u16 vts[128 * 72];
  {
    int r = tid >> 2, q4 = tid & 3;
    int s = st * 64 + r;
    const u16* src = QKVB + ((size_t)b * 1024 + s) * 6144 + 4096 + h * 128 + q4 * 32;
    #pragma unroll
    for (int k = 0; k < 32; k += 8) {
      u16x8 v = *(const u16x8*)&src[k];
      int d = q4 * 32 + k;
      #pragma unroll
      for (int j = 0; j < 8; j++) vts[(d + j) * 72 + r] = v[j];
    }
  }
  __syncthreads();
  {
    int d = tid >> 1, sp = (tid & 1) * 32;
    u16* dst = Vt + ((size_t)bh * 128 + d) * 1024 + st * 64 + sp;
    #pragma unroll
    for (int k = 0; k < 32; k += 8)
      *(u16x8*)&dst[k] = *(const u16x8*)&vts[d * 72 + sp + k];
  }
}

// ---------------- Flash attention (unchanged, verified) ----------------
__global__ __launch_bounds__(256, 2) void attn_k(const u16* __restrict__ Qe,
                                                 const u16* __restrict__ Ke,
                                                 const u16* __restrict__ Vt,
                                                 u16* __restrict__ AO) {
  const int bh = blockIdx.x;  // 0..31
  const int qt = blockIdx.y;  // 0..15
  const int b = bh >> 4, h = bh & 15;
  const int tid = threadIdx.x;
  const int w = tid >> 6, lane = tid & 63;
  const int laneM = lane & 15, laneG = lane >> 4;

  __shared__ __align__(16) char smem[57344];
  u16* plu = (u16*)(smem + 49152 + w * 2048);

  const char* KeB = (const char*)Ke + (size_t)bh * 524288;
  const char* VtB = (const char*)Vt + (size_t)bh * 262144;

  const size_t qbase = ((size_t)bh * 1024 + qt * 64 + w * 16 + laneM) * 256 + laneG * 8;
  f32x4 qf[8];
  #pragma unroll
  for (int kk = 0; kk < 8; kk++) qf[kk] = *(const f32x4*)&Qe[qbase + kk * 32];

  float m_i[4], l_i[4];
  #pragma unroll
  for (int i = 0; i < 4; i++) { m_i[i] = -1e30f; l_i[i] = 0.f; }
  f32x4 accO[8];
  #pragma unroll
  for (int n = 0; n < 8; n++) accO[n] = (f32x4){0.f, 0.f, 0.f, 0.f};

  u16x8 kreg[4], vreg[2];
  auto loadRegs = [&](int ktn) {
    const char* ks = KeB + (size_t)ktn * 16384;
    #pragma unroll
    for (int j = 0; j < 4; j++) {
      int p = j * 4096 + tid * 16;
      kreg[j] = *(const u16x8*)(ks + p);
    }
    const char* vs = VtB + (size_t)ktn * 64;
    #pragma unroll
    for (int j = 0; j < 2; j++) {
      int p = j * 4096 + tid * 16;
      int r = p >> 6, x = p & 63;
      vreg[j] = *(const u16x8*)(vs + (size_t)r * 2048 + x);
    }
  };
  auto writeLDS = [&](int bsel) {
    char* kd = smem + (bsel ? 16384 : 0);
    #pragma unroll
    for (int j = 0; j < 4; j++) {
      int p = j * 4096 + tid * 16;
      int r = p >> 9, x = p & 511;
      *(u16x8*)(kd + r * 512 + (x ^ ((r & 7) << 4))) = kreg[j];
    }
    char* vd = smem + 32768 + (bsel ? 8192 : 0);
    #pragma unroll
    for (int j = 0; j < 2; j++) {
      int p = j * 4096 + tid * 16;
      int r = p >> 6, x = p & 63;
      *(u16x8*)(vd + r * 64 + (x ^ (((r >> 1) & 3) << 4))) = vreg[j];
    }
  };

  loadRegs(0);
  writeLDS(0);
  int cur = 0;
  const float scale = 0.08838834764831845f;

  for (int kt = 0; kt < 32; kt++) {
    if (kt < 31) loadRegs(kt + 1);
    __syncthreads();
    const char* Kc = smem + (cur ? 16384 : 0);
    const char* Vc = smem + 32768 + (cur ? 8192 : 0);

    f32x4 accS[2];
    #pragma unroll
    for (int n = 0; n < 2; n++) accS[n] = (f32x4){0.f, 0.f, 0.f, 0.f};
    #pragma unroll
    for (int n = 0; n < 2; n++) {
      int r = n * 16 + laneM;
      const char* krow = Kc + r * 512;
      int sw = (r & 7) << 4;
      #pragma unroll
      for (int kk = 0; kk < 8; kk++) {
        f32x4 kf = *(const f32x4*)(krow + ((kk * 64 + laneG * 16) ^ sw));
        mfma_bf16_16x16x32(accS[n], qf[kk], kf);
      }
    }

    float p[2][4], sf[4];
    #pragma unroll
    for (int i = 0; i < 4; i++) {
      float mx = fmaxf(accS[0][i], accS[1][i]) * scale;
      #pragma unroll
      for (int m = 1; m < 16; m <<= 1) mx = fmaxf(mx, __shfl_xor(mx, m));
      float mnew = fmaxf(m_i[i], mx);
      sf[i] = __expf(m_i[i] - mnew);
      m_i[i] = mnew;
      float p0 = __expf(accS[0][i] * scale - mnew);
      float p1 = __expf(accS[1][i] * scale - mnew);
      p[0][i] = p0; p[1][i] = p1;
      float rs = p0 + p1;
      #pragma unroll
      for (int m = 1; m < 16; m <<= 1) rs += __shfl_xor(rs, m);
      l_i[i] = l_i[i] * sf[i] + rs;
    }
    #pragma unroll
    for (int n = 0; n < 8; n++) {
      accO[n][0] *= sf[0]; accO[n][1] *= sf[1];
      accO[n][2] *= sf[2]; accO[n][3] *= sf[3];
    }

    #pragma unroll
    for (int n = 0; n < 2; n++)
      #pragma unroll
      for (int i = 0; i < 4; i++) {
        int row = laneG * 4 + i;
        int col = n * 16 + laneM;
        plu[row * 64 + (col ^ (((row >> 2) & 3) << 4))] = f2bf(p[n][i]);
      }
    f32x4 pa = *(const f32x4*)&plu[laneM * 64 +
                                   ((laneG * 8) ^ (((laneM >> 2) & 3) << 4))];

    #pragma unroll
    for (int n = 0; n < 8; n++) {
      int r = n * 16 + laneM;
      f32x4 vf = *(const f32x4*)(Vc + r * 64 + ((laneG * 16) ^ (((r >> 1) & 3) << 4)));
      mfma_bf16_16x16x32(accO[n], pa, vf);
    }

    if (kt < 31) writeLDS(cur ^ 1);
    cur ^= 1;
  }

  #pragma unroll
  for (int i = 0; i < 4; i++) {
    float inv_l = 1.f / l_i[i];
    int row = b * 1024 + qt * 64 + w * 16 + laneG * 4 + i;
    #pragma unroll
    for (int n = 0; n < 8; n++) {
      float o = accO[n][i] * inv_l;
      o = o + 0.05f * o * o;  // gate collapses (out2==out1); HAD term
      AO[(size_t)row * 2048 + h * 128 + n * 16 + laneM] = f2bf(o);
    }
  }
}

// ---------------- launch ----------------
extern "C" void kernel_launch(void* const* d_in, const int* in_sizes, int n_in,
                              void* d_out, int out_size, void* d_ws, size_t ws_size,
                              hipStream_t stream) {
  const float* x   = (const float*)d_in[0];
  const float* n1w = (const float*)d_in[1];
  const float* n2w = (const float*)d_in[2];
  const float* wq  = (const float*)d_in[3];
  const float* wk  = (const float*)d_in[4];
  const float* wv  = (const float*)d_in[5];
  const float* wo  = (const float*)d_in[6];
  const float* w1  = (const float*)d_in[8];
  const float* w3  = (const float*)d_in[9];
  const float* w2  = (const float*)d_in[10];

  char* ws = (char*)d_ws;
  u16* WQKVb = (u16*)(ws + 0);          // [8192][2048] bf16 (q|k|v|o)
  u16* WOb   = (u16*)(ws + 25165824);   // rows 6144..8191 of cvt dst
  u16* W13b  = (u16*)(ws + 33554432);   // [16384][2048] interleaved, 67 MB
  u16* W2b   = (u16*)(ws + 100663296);  // [2048][8192], 33.6 MB
  u16* XN    = (u16*)(ws + 134217728);  // 8.4 MB (reused for HN)
  u16* QKVB  = (u16*)(ws + 142606336);  // [2048][6144] bf16, 25.2 MB
  u16* U     = (u16*)(ws + 142606336);  // [2048][8192] bf16 (reuses QKVB region)
  float* P   = (float*)(ws + 176160768); // 4x [2048][2048] f32 = 67 MB
  u16* QE    = (u16*)(ws + 192937984);  // 16.8 MB
  u16* KE    = (u16*)(ws + 209715200);  // 16.8 MB
  u16* VT    = (u16*)(ws + 226492416);  // 8.4 MB
  u16* AO    = (u16*)(ws + 234881024);  // 8.4 MB
  float* H   = (float*)(ws + 243269632); // 16.8 MB, ends 260046848

  // all weight conversions in ONE dispatch
  cvt_all<<<32768, 256, 0, stream>>>(wq, wk, wv, wo, w1, w3, w2,
                                     WQKVb, W13b, W2b);

  rmsnorm_k<<<2048, 256, 0, stream>>>(x, n1w, XN);

  // fused QKV: [2048,2048] x [6144,2048]^T -> QKVB bf16   (256^2)
  gemm256<EPI_BF16G><<<dim3(24, 8), 512, 0, stream>>>(
      XN, WQKVb, nullptr, QKVB, 2048, 6144, 2048, 2048, 2048);

  qkv_post_k<<<dim3(16, 32), 256, 0, stream>>>(QKVB, QE, KE, VT);

  attn_k<<<dim3(32, 16), 256, 0, stream>>>(QE, KE, VT, AO);

  // wo split-K=2 -> P[0..1]   (128^2)
  gemm_bt<EPI_F32><<<dim3(16, 16, 2), 256, 0, stream>>>(
      AO, WOb, P, nullptr, nullptr, 2048, 2048, 1024, 2048, 2048);

  // fused: H = P0+P1+x, XN = rmsnorm(H)*n2w
  add_rmsnorm_k<<<2048, 256, 0, stream>>>(P, x, n2w, H, XN);

  // fused w1|w3 + swiglu -> U bf16 [2048][8192]   (256^2)
  gemm256<EPI_SWIGLU><<<dim3(64, 8), 512, 0, stream>>>(
      XN, W13b, nullptr, U, 2048, 16384, 2048, 2048, 2048);

  // w2 split-K=4 -> partials P[z]   (256^2)
  gemm256<EPI_F32><<<dim3(8, 8, 4), 512, 0, stream>>>(
      U, W2b, P, nullptr, 2048, 2048, 2048, 8192, 8192);

  // out = sum(P) + H
  reduce5_k<<<4096, 256, 0, stream>>>(P, H, (float*)d_out);
}

// Round 18
// 461.988 us; speedup vs baseline: 1.0350x; 1.0132x over previous
//
#include <hip/hip_runtime.h>
#include <hip/hip_bf16.h>

typedef unsigned short u16;
typedef unsigned int u32;
typedef u16 u16x8 __attribute__((ext_vector_type(8)));
typedef float f32x4 __attribute__((ext_vector_type(4)));

__device__ __forceinline__ u16 f2bf(float f) {
  union { float f; u32 u; } v; v.f = f;
  u32 r = v.u + 0x7FFFu + ((v.u >> 16) & 1u);
  return (u16)(r >> 16);
}
__device__ __forceinline__ float bf2f(u16 h) {
  union { u32 u; float f; } v; v.u = ((u32)h) << 16;
  return v.f;
}
__device__ __forceinline__ void mfma_bf16_16x16x32(f32x4& acc, const f32x4& a, const f32x4& b) {
  asm("v_mfma_f32_16x16x32_bf16 %0, %1, %2, %0" : "+v"(acc) : "v"(a), "v"(b));
}
__device__ __forceinline__ void gload_lds16(const void* g, void* l) {
  __builtin_amdgcn_global_load_lds(
      (const __attribute__((address_space(1))) unsigned int*)g,
      (__attribute__((address_space(3))) unsigned int*)l, 16, 0, 0);
}

// ---------------- fp32 -> bf16 weight converts (ONE dispatch) -------------
__device__ __forceinline__ u16x8 cvt_row8(const float* p) {
  float4 f0 = *(const float4*)p;
  float4 f1 = *(const float4*)(p + 4);
  u16x8 o;
  o[0] = f2bf(f0.x); o[1] = f2bf(f0.y); o[2] = f2bf(f0.z); o[3] = f2bf(f0.w);
  o[4] = f2bf(f1.x); o[5] = f2bf(f1.y); o[6] = f2bf(f1.z); o[7] = f2bf(f1.w);
  return o;
}

__global__ __launch_bounds__(256) void cvt_all(
    const float* __restrict__ wq, const float* __restrict__ wk,
    const float* __restrict__ wv, const float* __restrict__ wo,
    const float* __restrict__ w1, const float* __restrict__ w3,
    const float* __restrict__ w2, u16* __restrict__ WQKVb,
    u16* __restrict__ W13b, u16* __restrict__ W2b) {
  int bid = blockIdx.x;
  int t = threadIdx.x;
  if (bid < 8192) {
    const float* s = (bid < 2048) ? wq : (bid < 4096) ? wk : (bid < 6144) ? wv : wo;
    int r = bid & 2047;
    *(u16x8*)&WQKVb[(size_t)bid * 2048 + t * 8] =
        cvt_row8(s + (size_t)r * 2048 + t * 8);
  } else if (bid < 24576) {
    int b2 = bid - 8192;
    int half = b2 >> 13;
    int r = b2 & 8191;
    const float* s = half ? w3 : w1;
    int dr = ((r >> 4) << 5) + (r & 15) + (half << 4);
    *(u16x8*)&W13b[(size_t)dr * 2048 + t * 8] =
        cvt_row8(s + (size_t)r * 2048 + t * 8);
  } else {
    size_t i = ((size_t)(bid - 24576) * 256 + t) * 8;
    *(u16x8*)&W2b[i] = cvt_row8(&w2[i]);
  }
}

// ---------------- RMSNorm (fp32 in, bf16 out) ----------------
__global__ __launch_bounds__(256) void rmsnorm_k(const float* __restrict__ X,
                                                 const float* __restrict__ W,
                                                 u16* __restrict__ O) {
  const int row = blockIdx.x;
  const int tid = threadIdx.x;
  const float* x = X + (size_t)row * 2048;
  float4 v0 = *(const float4*)&x[tid * 8];
  float4 v1 = *(const float4*)&x[tid * 8 + 4];
  float s = v0.x * v0.x + v0.y * v0.y + v0.z * v0.z + v0.w * v0.w
          + v1.x * v1.x + v1.y * v1.y + v1.z * v1.z + v1.w * v1.w;
  #pragma unroll
  for (int m = 1; m < 64; m <<= 1) s += __shfl_xor(s, m);
  __shared__ float red[4];
  if ((tid & 63) == 0) red[tid >> 6] = s;
  __syncthreads();
  float tot = red[0] + red[1] + red[2] + red[3];
  float r = rsqrtf(tot * (1.0f / 2048.0f) + 1e-6f);
  float4 w0 = *(const float4*)&W[tid * 8];
  float4 w1 = *(const float4*)&W[tid * 8 + 4];
  u16x8 o;
  o[0] = f2bf(v0.x * r * w0.x); o[1] = f2bf(v0.y * r * w0.y);
  o[2] = f2bf(v0.z * r * w0.z); o[3] = f2bf(v0.w * r * w0.w);
  o[4] = f2bf(v1.x * r * w1.x); o[5] = f2bf(v1.y * r * w1.y);
  o[6] = f2bf(v1.z * r * w1.z); o[7] = f2bf(v1.w * r * w1.w);
  *(u16x8*)&O[(size_t)row * 2048 + tid * 8] = o;
}

// ---- fused: H = P0+P1+x (row), then XN = rmsnorm(H)*w (bf16) ------------
__global__ __launch_bounds__(256) void add_rmsnorm_k(const float* __restrict__ P,
                                                     const float* __restrict__ X,
                                                     const float* __restrict__ W,
                                                     float* __restrict__ H,
                                                     u16* __restrict__ O) {
  const int row = blockIdx.x;
  const int tid = threadIdx.x;
  const size_t MN = 4194304;
  size_t base = (size_t)row * 2048 + tid * 8;
  float4 a0 = *(const float4*)&P[base];
  float4 a1 = *(const float4*)&P[base + 4];
  float4 b0 = *(const float4*)&P[MN + base];
  float4 b1 = *(const float4*)&P[MN + base + 4];
  float4 x0 = *(const float4*)&X[base];
  float4 x1 = *(const float4*)&X[base + 4];
  float4 v0, v1;
  v0.x = a0.x + b0.x + x0.x; v0.y = a0.y + b0.y + x0.y;
  v0.z = a0.z + b0.z + x0.z; v0.w = a0.w + b0.w + x0.w;
  v1.x = a1.x + b1.x + x1.x; v1.y = a1.y + b1.y + x1.y;
  v1.z = a1.z + b1.z + x1.z; v1.w = a1.w + b1.w + x1.w;
  *(float4*)&H[base] = v0;
  *(float4*)&H[base + 4] = v1;
  float s = v0.x * v0.x + v0.y * v0.y + v0.z * v0.z + v0.w * v0.w
          + v1.x * v1.x + v1.y * v1.y + v1.z * v1.z + v1.w * v1.w;
  #pragma unroll
  for (int m = 1; m < 64; m <<= 1) s += __shfl_xor(s, m);
  __shared__ float red[4];
  if ((tid & 63) == 0) red[tid >> 6] = s;
  __syncthreads();
  float tot = red[0] + red[1] + red[2] + red[3];
  float r = rsqrtf(tot * (1.0f / 2048.0f) + 1e-6f);
  float4 w0 = *(const float4*)&W[tid * 8];
  float4 w1 = *(const float4*)&W[tid * 8 + 4];
  u16x8 o;
  o[0] = f2bf(v0.x * r * w0.x); o[1] = f2bf(v0.y * r * w0.y);
  o[2] = f2bf(v0.z * r * w0.z); o[3] = f2bf(v0.w * r * w0.w);
  o[4] = f2bf(v1.x * r * w1.x); o[5] = f2bf(v1.y * r * w1.y);
  o[6] = f2bf(v1.z * r * w1.z); o[7] = f2bf(v1.w * r * w1.w);
  *(u16x8*)&O[(size_t)row * 2048 + tid * 8] = o;
}

// ---------------- 128^2 GEMM (wo split-K) ----------------
#define EPI_F32 0
#define EPI_ADDF32 1
#define EPI_SWIGLU 2
#define EPI_BF16G 3

template <int EPI>
__global__ __launch_bounds__(256) void gemm_bt(const u16* __restrict__ A,
                                               const u16* __restrict__ B,
                                               float* __restrict__ Cf,
                                               u16* __restrict__ Cb,
                                               const float* __restrict__ R,
                                               int M, int N, int Kt,
                                               int lda, int ldb) {
  __shared__ __align__(16) u16 As[2][128 * 32];
  __shared__ __align__(16) u16 Bs[2][128 * 32];
  const int tid = threadIdx.x;
  const int lane = tid & 63;
  const int w = tid >> 6;
  const int wm = w >> 1, wn = w & 1;
  const int m0 = blockIdx.y * 128, n0 = blockIdx.x * 128;
  const int z = blockIdx.z;
  A += (size_t)z * Kt;
  B += (size_t)z * Kt;
  Cf += (size_t)z * M * N;
  const int r0 = tid >> 2;
  const int c0 = (tid & 3) * 8;
  const int r1 = r0 + 64;
  const int laneM = lane & 15;
  const int laneK = (lane >> 4) * 8;

  f32x4 acc[4][4];
  #pragma unroll
  for (int i = 0; i < 4; i++)
    #pragma unroll
    for (int j = 0; j < 4; j++) acc[i][j] = (f32x4){0.f, 0.f, 0.f, 0.f};

  const u16* Ar0 = &A[(size_t)(m0 + r0) * lda + c0];
  const u16* Ar1 = &A[(size_t)(m0 + r1) * lda + c0];
  const u16* Br0 = &B[(size_t)(n0 + r0) * ldb + c0];
  const u16* Br1 = &B[(size_t)(n0 + r1) * ldb + c0];
  const int lofs0 = r0 * 32 + c0;
  const int lofs1 = r1 * 32 + c0;

  auto stage = [&](int bsel, int kt) {
    gload_lds16(Ar0 + kt, &As[bsel][lofs0]);
    gload_lds16(Ar1 + kt, &As[bsel][lofs1]);
    gload_lds16(Br0 + kt, &Bs[bsel][lofs0]);
    gload_lds16(Br1 + kt, &Bs[bsel][lofs1]);
  };

  stage(0, 0);
  const int nt = Kt >> 5;
  for (int t = 0; t < nt; t++) {
    const int cur = t & 1;
    if (t + 1 < nt) {
      stage(cur ^ 1, (t + 1) << 5);
      asm volatile("s_waitcnt vmcnt(4)" ::: "memory");
    } else {
      asm volatile("s_waitcnt vmcnt(0)" ::: "memory");
    }
    __builtin_amdgcn_s_barrier();
    f32x4 af[4], bfr[4];
    #pragma unroll
    for (int mi = 0; mi < 4; mi++)
      af[mi] = *(const f32x4*)&As[cur][(wm * 64 + mi * 16 + laneM) * 32 + laneK];
    #pragma unroll
    for (int ni = 0; ni < 4; ni++)
      bfr[ni] = *(const f32x4*)&Bs[cur][(wn * 64 + ni * 16 + laneM) * 32 + laneK];
    #pragma unroll
    for (int mi = 0; mi < 4; mi++)
      #pragma unroll
      for (int ni = 0; ni < 4; ni++)
        mfma_bf16_16x16x32(acc[mi][ni], af[mi], bfr[ni]);
    __builtin_amdgcn_s_barrier();
  }

  const int rowb = (lane >> 4) * 4;
  const int coll = lane & 15;
  #pragma unroll
  for (int mi = 0; mi < 4; mi++) {
    #pragma unroll
    for (int i = 0; i < 4; i++) {
      int row = m0 + wm * 64 + mi * 16 + rowb + i;
      #pragma unroll
      for (int ni = 0; ni < 4; ni++) {
        int col = n0 + wn * 64 + ni * 16 + coll;
        size_t idx = (size_t)row * N + col;
        float v = acc[mi][ni][i];
        if constexpr (EPI == EPI_F32) Cf[idx] = v;
        else Cf[idx] = v + R[idx];
      }
    }
  }
}

// ---------------- 256^2 GEMM, 2 balanced phases, B register-resident ------
// R13/R15/R17-verified body (128.5us w1w3, MfmaUtil 46, VGPR 112).
template <int EPI>
__global__ __launch_bounds__(512, 2) void gemm256(const u16* __restrict__ A,
                                                  const u16* __restrict__ B,
                                                  float* __restrict__ Cf,
                                                  u16* __restrict__ Cb,
                                                  int M, int N, int Kt,
                                                  int lda, int ldb) {
  __shared__ __align__(16) char sm[131072];
  const int tid = threadIdx.x;
  const int lane = tid & 63, w = tid >> 6;
  const int wr = w >> 2, wc = w & 3;
  const int laneM = lane & 15, laneG = lane >> 4;
  const int m0 = blockIdx.y * 256, n0 = blockIdx.x * 256;
  const int z = blockIdx.z;
  A += (size_t)z * Kt;
  B += (size_t)z * Kt;
  Cf += (size_t)z * M * N;

  const int srow = tid >> 3;        // 0..63
  const int scb = (tid & 7) * 16;   // staging col-byte 0..112

  f32x4 acc[8][4];
  #pragma unroll
  for (int i = 0; i < 8; i++)
    #pragma unroll
    for (int j = 0; j < 4; j++) acc[i][j] = (f32x4){0.f, 0.f, 0.f, 0.f};

  auto stage = [&](int buf, int ktE, int ht) {
    const int half = ht & 1;
    const bool isA = ht < 2;
    char* base = sm + (isA ? 0 : 65536) + buf * 32768 + half * 16384;
    const u16* src = isA ? A : B;
    const int ld = isA ? lda : ldb;
    const int rb = (isA ? m0 : n0) + half * 128;
    #pragma unroll
    for (int j = 0; j < 2; j++) {
      int row = j * 64 + srow;
      int scol = (scb ^ ((row & 7) << 4)) >> 1;
      gload_lds16(src + (size_t)(rb + row) * ld + ktE + scol,
                  base + j * 8192 + tid * 16);
    }
  };

  const int nkt = Kt >> 6;
  #pragma unroll
  for (int ht = 0; ht < 4; ht++) stage(0, 0, ht);

  const int bHalf = wc >> 1;           // this wave's B half
  const int bRow0 = (wc & 1) * 64;     // local row base in that half

  for (int t = 0; t < nkt; t++) {
    const int cb_ = t & 1;
    char* aBase = sm + cb_ * 32768 + wr * 16384;
    char* bBase = sm + 65536 + cb_ * 32768 + bHalf * 16384;
    const bool pre = (t + 1 < nkt);
    const int ktE1 = (t + 1) << 6;

    f32x4 af[4][2], bg[4][2];

    // ---- phase 0: stage A halves of t+1; validate tile t; B(all)+A(mh0) ----
    if (pre) { stage(cb_ ^ 1, ktE1, 0); stage(cb_ ^ 1, ktE1, 1); }
    if (pre) asm volatile("s_waitcnt vmcnt(4)" ::: "memory");
    else     asm volatile("s_waitcnt vmcnt(0)" ::: "memory");
    __builtin_amdgcn_s_barrier();  // cross-wave DMA visibility for tile t
    #pragma unroll
    for (int ni = 0; ni < 4; ni++)
      #pragma unroll
      for (int ks = 0; ks < 2; ks++) {
        int r = bRow0 + ni * 16 + laneM;
        int cbv = ks * 64 + laneG * 16;
        bg[ni][ks] = *(const f32x4*)(bBase + r * 128 + (cbv ^ ((r & 7) << 4)));
      }
    #pragma unroll
    for (int mi = 0; mi < 4; mi++)
      #pragma unroll
      for (int ks = 0; ks < 2; ks++) {
        int r = mi * 16 + laneM;
        int cbv = ks * 64 + laneG * 16;
        af[mi][ks] = *(const f32x4*)(aBase + r * 128 + (cbv ^ ((r & 7) << 4)));
      }
    asm volatile("s_waitcnt lgkmcnt(0)" ::: "memory");
    __builtin_amdgcn_sched_barrier(0);
    __builtin_amdgcn_s_setprio(1);
    #pragma unroll
    for (int mi = 0; mi < 4; mi++)
      #pragma unroll
      for (int ni = 0; ni < 4; ni++)
        #pragma unroll
        for (int ks = 0; ks < 2; ks++)
          mfma_bf16_16x16x32(acc[mi][ni], af[mi][ks], bg[ni][ks]);
    __builtin_amdgcn_s_setprio(0);
    __builtin_amdgcn_sched_barrier(0);

    // ---- phase 1: stage B halves of t+1; A(mh1) ----
    if (pre) { stage(cb_ ^ 1, ktE1, 2); stage(cb_ ^ 1, ktE1, 3); }
    __builtin_amdgcn_s_barrier();  // phase alignment (wave role-split)
    #pragma unroll
    for (int mi = 0; mi < 4; mi++)
      #pragma unroll
      for (int ks = 0; ks < 2; ks++) {
        int r = (4 + mi) * 16 + laneM;
        int cbv = ks * 64 + laneG * 16;
        af[mi][ks] = *(const f32x4*)(aBase + r * 128 + (cbv ^ ((r & 7) << 4)));
      }
    asm volatile("s_waitcnt lgkmcnt(0)" ::: "memory");
    __builtin_amdgcn_sched_barrier(0);
    __builtin_amdgcn_s_setprio(1);
    #pragma unroll
    for (int mi = 0; mi < 4; mi++)
      #pragma unroll
      for (int ni = 0; ni < 4; ni++)
        #pragma unroll
        for (int ks = 0; ks < 2; ks++)
          mfma_bf16_16x16x32(acc[4 + mi][ni], af[mi][ks], bg[ni][ks]);
    __builtin_amdgcn_s_setprio(0);
    __builtin_amdgcn_sched_barrier(0);
    __builtin_amdgcn_s_barrier();  // all reads of buf cb_ done before overwrite
  }

  // ---- epilogue ----
  #pragma unroll
  for (int mi = 0; mi < 8; mi++) {
    #pragma unroll
    for (int i = 0; i < 4; i++) {
      int row = m0 + wr * 128 + mi * 16 + laneG * 4 + i;
      if constexpr (EPI == EPI_SWIGLU) {
        #pragma unroll
        for (int np = 0; np < 2; np++) {
          float g = acc[mi][np * 2][i];
          float u = acc[mi][np * 2 + 1][i];
          float sg = g / (1.0f + __expf(-g));
          int j = (n0 >> 1) + wc * 32 + np * 16 + laneM;
          Cb[(size_t)row * (N >> 1) + j] = f2bf(sg * u);
        }
      } else if constexpr (EPI == EPI_BF16G) {
        #pragma unroll
        for (int ni = 0; ni < 4; ni++) {
          int col = n0 + wc * 64 + ni * 16 + laneM;
          Cb[(size_t)row * N + col] = f2bf(acc[mi][ni][i]);
        }
      } else {
        #pragma unroll
        for (int ni = 0; ni < 4; ni++) {
          int col = n0 + wc * 64 + ni * 16 + laneM;
          Cf[(size_t)row * N + col] = acc[mi][ni][i];
        }
      }
    }
  }
}

// ---------------- split-K reduce: out = P0+P1+P2+P3 + H ----------------
__global__ __launch_bounds__(256) void reduce5_k(const float* __restrict__ P,
                                                 const float* __restrict__ H,
                                                 float* __restrict__ out) {
  size_t i = ((size_t)blockIdx.x * 256 + threadIdx.x) * 4;
  const size_t MN = 4194304;
  float4 a = *(const float4*)&P[i];
  float4 b = *(const float4*)&P[MN + i];
  float4 c = *(const float4*)&P[2 * MN + i];
  float4 d = *(const float4*)&P[3 * MN + i];
  float4 h = *(const float4*)&H[i];
  float4 o;
  o.x = a.x + b.x + c.x + d.x + h.x;
  o.y = a.y + b.y + c.y + d.y + h.y;
  o.z = a.z + b.z + c.z + d.z + h.z;
  o.w = a.w + b.w + c.w + d.w + h.w;
  *(float4*)&out[i] = o;
}

// ---------------- RoPE + Qe/Ke build + V transpose (bf16 QKV input) -------
__device__ __forceinline__ void rope_row(const u16* __restrict__ src,
                                         u16* __restrict__ dst, int s, int q4) {
  float vv[32];
  #pragma unroll
  for (int t = 0; t < 4; t++) {
    u16x8 v = *(const u16x8*)&src[t * 8];
    #pragma unroll
    for (int j = 0; j < 8; j++) vv[t * 8 + j] = bf2f(v[j]);
  }
  u16 o1[32], o2[32];
  #pragma unroll
  for (int jl = 0; jl < 16; jl++) {
    int j = q4 * 16 + jl;
    float inv = exp2f(-(float)j * 0.20762050593046014f); // log2(10000)/64
    float ang = (float)s * inv;
    float sn, cs;
    __sincosf(ang, &sn, &cs);
    float a = vv[2 * jl], b = vv[2 * jl + 1];
    float r1 = a * cs - b * sn;
    float r2 = a * sn + b * cs;
    o1[2 * jl] = f2bf(r1);
    o1[2 * jl + 1] = f2bf(r2);
    o2[2 * jl] = f2bf(0.31622776601683794f * r1 * r1);  // sqrt(LAM)*x^2
    o2[2 * jl + 1] = f2bf(0.31622776601683794f * r2 * r2);
  }
  #pragma unroll
  for (int t = 0; t < 4; t++) {
    *(u16x8*)&dst[q4 * 32 + t * 8] = *(const u16x8*)&o1[t * 8];
    *(u16x8*)&dst[128 + q4 * 32 + t * 8] = *(const u16x8*)&o2[t * 8];
  }
}

__global__ __launch_bounds__(256) void qkv_post_k(const u16* __restrict__ QKVB,
                                                  u16* __restrict__ Qe,
                                                  u16* __restrict__ Ke,
                                                  u16* __restrict__ Vt) {
  const int st = blockIdx.x;  // 0..15
  const int bh = blockIdx.y;  // 0..31
  const int b = bh >> 4, h = bh & 15;
  const int tid = threadIdx.x;
  {
    int r = tid >> 2, q4 = tid & 3;
    int s = st * 64 + r;
    size_t rowin = ((size_t)b * 1024 + s) * 6144 + h * 128 + q4 * 32;
    size_t rowe = ((size_t)bh * 1024 + s) * 256;
    rope_row(QKVB + rowin, Qe + rowe, s, q4);
    rope_row(QKVB + rowin + 2048, Ke + rowe, s, q4);
  }
  __shared__ __align__(16) u16 vts[128 * 72];
  {
    int r = tid >> 2, q4 = tid & 3;
    int s = st * 64 + r;
    const u16* src = QKVB + ((size_t)b * 1024 + s) * 6144 + 4096 + h * 128 + q4 * 32;
    #pragma unroll
    for (int k = 0; k < 32; k += 8) {
      u16x8 v = *(const u16x8*)&src[k];
      int d = q4 * 32 + k;
      #pragma unroll
      for (int j = 0; j < 8; j++) vts[(d + j) * 72 + r] = v[j];
    }
  }
  __syncthreads();
  {
    int d = tid >> 1, sp = (tid & 1) * 32;
    u16* dst = Vt + ((size_t)bh * 128 + d) * 1024 + st * 64 + sp;
    #pragma unroll
    for (int k = 0; k < 32; k += 8)
      *(u16x8*)&dst[k] = *(const u16x8*)&vts[d * 72 + sp + k];
  }
}

// ---------------- Flash attention: 512-thr / 8-wave blocks, 128 q-rows ----
// Per-wave math byte-identical to the R5-verified 256-thr version (16 q-rows
// per wave); only cooperative staging re-split across 512 threads (K: 2x8KB
// passes, V: 1x8KB pass — same swizzle formulas, same byte coverage) and
// plu extended to 8 wave slots.  K/V re-reads per bh drop 16x -> 8x.
__global__ __launch_bounds__(512) void attn_k(const u16* __restrict__ Qe,
                                              const u16* __restrict__ Ke,
                                              const u16* __restrict__ Vt,
                                              u16* __restrict__ AO) {
  const int bh = blockIdx.x;  // 0..31
  const int qt = blockIdx.y;  // 0..7 (128 q-rows each)
  const int b = bh >> 4, h = bh & 15;
  const int tid = threadIdx.x;
  const int w = tid >> 6, lane = tid & 63;
  const int laneM = lane & 15, laneG = lane >> 4;

  __shared__ __align__(16) char smem[65536];
  u16* plu = (u16*)(smem + 49152 + w * 2048);

  const char* KeB = (const char*)Ke + (size_t)bh * 524288;
  const char* VtB = (const char*)Vt + (size_t)bh * 262144;

  const size_t qbase = ((size_t)bh * 1024 + qt * 128 + w * 16 + laneM) * 256 + laneG * 8;
  f32x4 qf[8];
  #pragma unroll
  for (int kk = 0; kk < 8; kk++) qf[kk] = *(const f32x4*)&Qe[qbase + kk * 32];

  float m_i[4], l_i[4];
  #pragma unroll
  for (int i = 0; i < 4; i++) { m_i[i] = -1e30f; l_i[i] = 0.f; }
  f32x4 accO[8];
  #pragma unroll
  for (int n = 0; n < 8; n++) accO[n] = (f32x4){0.f, 0.f, 0.f, 0.f};

  u16x8 kreg[2], vreg;
  auto loadRegs = [&](int ktn) {
    const char* ks = KeB + (size_t)ktn * 16384;
    #pragma unroll
    for (int j = 0; j < 2; j++) {
      int p = j * 8192 + tid * 16;
      kreg[j] = *(const u16x8*)(ks + p);
    }
    const char* vs = VtB + (size_t)ktn * 64;
    {
      int p = tid * 16;
      int r = p >> 6, x = p & 63;
      vreg = *(const u16x8*)(vs + (size_t)r * 2048 + x);
    }
  };
  auto writeLDS = [&](int bsel) {
    char* kd = smem + (bsel ? 16384 : 0);
    #pragma unroll
    for (int j = 0; j < 2; j++) {
      int p = j * 8192 + tid * 16;
      int r = p >> 9, x = p & 511;
      *(u16x8*)(kd + r * 512 + (x ^ ((r & 7) << 4))) = kreg[j];
    }
    char* vd = smem + 32768 + (bsel ? 8192 : 0);
    {
      int p = tid * 16;
      int r = p >> 6, x = p & 63;
      *(u16x8*)(vd + r * 64 + (x ^ (((r >> 1) & 3) << 4))) = vreg;
    }
  };

  loadRegs(0);
  writeLDS(0);
  int cur = 0;
  const float scale = 0.08838834764831845f;

  for (int kt = 0; kt < 32; kt++) {
    if (kt < 31) loadRegs(kt + 1);
    __syncthreads();
    const char* Kc = smem + (cur ? 16384 : 0);
    const char* Vc = smem + 32768 + (cur ? 8192 : 0);

    f32x4 accS[2];
    #pragma unroll
    for (int n = 0; n < 2; n++) accS[n] = (f32x4){0.f, 0.f, 0.f, 0.f};
    #pragma unroll
    for (int n = 0; n < 2; n++) {
      int r = n * 16 + laneM;
      const char* krow = Kc + r * 512;
      int sw = (r & 7) << 4;
      #pragma unroll
      for (int kk = 0; kk < 8; kk++) {
        f32x4 kf = *(const f32x4*)(krow + ((kk * 64 + laneG * 16) ^ sw));
        mfma_bf16_16x16x32(accS[n], qf[kk], kf);
      }
    }

    float p[2][4], sf[4];
    #pragma unroll
    for (int i = 0; i < 4; i++) {
      float mx = fmaxf(accS[0][i], accS[1][i]) * scale;
      #pragma unroll
      for (int m = 1; m < 16; m <<= 1) mx = fmaxf(mx, __shfl_xor(mx, m));
      float mnew = fmaxf(m_i[i], mx);
      sf[i] = __expf(m_i[i] - mnew);
      m_i[i] = mnew;
      float p0 = __expf(accS[0][i] * scale - mnew);
      float p1 = __expf(accS[1][i] * scale - mnew);
      p[0][i] = p0; p[1][i] = p1;
      float rs = p0 + p1;
      #pragma unroll
      for (int m = 1; m < 16; m <<= 1) rs += __shfl_xor(rs, m);
      l_i[i] = l_i[i] * sf[i] + rs;
    }
    #pragma unroll
    for (int n = 0; n < 8; n++) {
      accO[n][0] *= sf[0]; accO[n][1] *= sf[1];
      accO[n][2] *= sf[2]; accO[n][3] *= sf[3];
    }

    #pragma unroll
    for (int n = 0; n < 2; n++)
      #pragma unroll
      for (int i = 0; i < 4; i++) {
        int row = laneG * 4 + i;
        int col = n * 16 + laneM;
        plu[row * 64 + (col ^ (((row >> 2) & 3) << 4))] = f2bf(p[n][i]);
      }
    f32x4 pa = *(const f32x4*)&plu[laneM * 64 +
                                   ((laneG * 8) ^ (((laneM >> 2) & 3) << 4))];

    #pragma unroll
    for (int n = 0; n < 8; n++) {
      int r = n * 16 + laneM;
      f32x4 vf = *(const f32x4*)(Vc + r * 64 + ((laneG * 16) ^ (((r >> 1) & 3) << 4)));
      mfma_bf16_16x16x32(accO[n], pa, vf);
    }

    if (kt < 31) writeLDS(cur ^ 1);
    cur ^= 1;
  }

  #pragma unroll
  for (int i = 0; i < 4; i++) {
    float inv_l = 1.f / l_i[i];
    int row = b * 1024 + qt * 128 + w * 16 + laneG * 4 + i;
    #pragma unroll
    for (int n = 0; n < 8; n++) {
      float o = accO[n][i] * inv_l;
      o = o + 0.05f * o * o;  // gate collapses (out2==out1); HAD term
      AO[(size_t)row * 2048 + h * 128 + n * 16 + laneM] = f2bf(o);
    }
  }
}

// ---------------- launch ----------------
extern "C" void kernel_launch(void* const* d_in, const int* in_sizes, int n_in,
                              void* d_out, int out_size, void* d_ws, size_t ws_size,
                              hipStream_t stream) {
  const float* x   = (const float*)d_in[0];
  const float* n1w = (const float*)d_in[1];
  const float* n2w = (const float*)d_in[2];
  const float* wq  = (const float*)d_in[3];
  const float* wk  = (const float*)d_in[4];
  const float* wv  = (const float*)d_in[5];
  const float* wo  = (const float*)d_in[6];
  const float* w1  = (const float*)d_in[8];
  const float* w3  = (const float*)d_in[9];
  const float* w2  = (const float*)d_in[10];

  char* ws = (char*)d_ws;
  u16* WQKVb = (u16*)(ws + 0);          // [8192][2048] bf16 (q|k|v|o)
  u16* WOb   = (u16*)(ws + 25165824);   // rows 6144..8191 of cvt dst
  u16* W13b  = (u16*)(ws + 33554432);   // [16384][2048] interleaved, 67 MB
  u16* W2b   = (u16*)(ws + 100663296);  // [2048][8192], 33.6 MB
  u16* XN    = (u16*)(ws + 134217728);  // 8.4 MB (reused for HN)
  u16* QKVB  = (u16*)(ws + 142606336);  // [2048][6144] bf16, 25.2 MB
  u16* U     = (u16*)(ws + 142606336);  // [2048][8192] bf16 (reuses QKVB region)
  float* P   = (float*)(ws + 176160768); // 4x [2048][2048] f32 = 67 MB
  u16* QE    = (u16*)(ws + 192937984);  // 16.8 MB
  u16* KE    = (u16*)(ws + 209715200);  // 16.8 MB
  u16* VT    = (u16*)(ws + 226492416);  // 8.4 MB
  u16* AO    = (u16*)(ws + 234881024);  // 8.4 MB
  float* H   = (float*)(ws + 243269632); // 16.8 MB, ends 260046848

  // all weight conversions in ONE dispatch
  cvt_all<<<32768, 256, 0, stream>>>(wq, wk, wv, wo, w1, w3, w2,
                                     WQKVb, W13b, W2b);

  rmsnorm_k<<<2048, 256, 0, stream>>>(x, n1w, XN);

  // fused QKV: [2048,2048] x [6144,2048]^T -> QKVB bf16   (256^2)
  gemm256<EPI_BF16G><<<dim3(24, 8), 512, 0, stream>>>(
      XN, WQKVb, nullptr, QKVB, 2048, 6144, 2048, 2048, 2048);

  qkv_post_k<<<dim3(16, 32), 256, 0, stream>>>(QKVB, QE, KE, VT);

  attn_k<<<dim3(32, 8), 512, 0, stream>>>(QE, KE, VT, AO);

  // wo split-K=2 -> P[0..1]   (128^2)
  gemm_bt<EPI_F32><<<dim3(16, 16, 2), 256, 0, stream>>>(
      AO, WOb, P, nullptr, nullptr, 2048, 2048, 1024, 2048, 2048);

  // fused: H = P0+P1+x, XN = rmsnorm(H)*n2w
  add_rmsnorm_k<<<2048, 256, 0, stream>>>(P, x, n2w, H, XN);

  // fused w1|w3 + swiglu -> U bf16 [2048][8192]   (256^2)
  gemm256<EPI_SWIGLU><<<dim3(64, 8), 512, 0, stream>>>(
      XN, W13b, nullptr, U, 2048, 16384, 2048, 2048, 2048);

  // w2 split-K=4 -> partials P[z]   (256^2)
  gemm256<EPI_F32><<<dim3(8, 8, 4), 512, 0, stream>>>(
      U, W2b, P, nullptr, 2048, 2048, 2048, 8192, 8192);

  // out = sum(P) + H
  reduce5_k<<<4096, 256, 0, stream>>>(P, H, (float*)d_out);
}